// Round 1
// baseline (208.313 us; speedup 1.0000x reference)
//
#include <hip/hip_runtime.h>

#define NPIX 409600   // 640*640
#define NB 8          // batch

// ---------------- workspace layout (4-byte words, per batch) ----------------
constexpr int OFF_H0    = 0;     // 2048 u32  level-0 histogram (key bits 31..21)
constexpr int OFF_H1    = 2048;  // 2048 u32  level-1 histogram (key bits 20..10)
constexpr int OFF_H2    = 4096;  // 1024 u32  level-2 histogram (key bits 9..0)
constexpr int OFF_KC    = 5120;  // 8 u32     kernel-mask counts per instance
constexpr int OFF_TC    = 5128;  // 8 u32     text-mask counts per instance
constexpr int OFF_KS    = 5136;  // 32 f32    kernel-mask sim sums (inst*4+c)
constexpr int OFF_AGG   = 5168;  // 8 f32     per-instance sum log1p(D)
constexpr int OFF_CPOS  = 5176;  // u32
constexpr int OFF_CPOSM = 5177;  // u32  pos & tm<=0.5
constexpr int OFF_CNEG  = 5178;  // u32
constexpr int OFF_NEGNUM= 5179;  // u32
constexpr int OFF_PFX0  = 5180;  // u32  (0xFFFFFFFF = fallback sentinel)
constexpr int OFF_K1    = 5181;  // u32
constexpr int OFF_PFX1  = 5182;  // u32
constexpr int OFF_K2    = 5183;  // u32
constexpr int OFF_TH    = 5184;  // f32  OHEM threshold
constexpr int OFF_FALL  = 5185;  // u32  fallback flag
constexpr int OFF_G     = 5186;  // 32 f32 centroids
constexpr int OFF_NV    = 5218;  // u32 n_valid
constexpr int OFF_VM    = 5219;  // u32 valid bitmask
constexpr int OFF_LDIS  = 5220;  // f32
constexpr int OFF_DICE  = 5221;  // 6 f32: at,bt,ct,ak,bk,ck
constexpr int PER_BATCH = 5376;  // padded

// map float -> uint monotone ascending (larger float -> larger key)
__device__ __forceinline__ unsigned mapf(float s) {
  unsigned b = __float_as_uint(s);
  return (b & 0x80000000u) ? ~b : (b | 0x80000000u);
}
__device__ __forceinline__ float unmapf(unsigned u) {
  return __uint_as_float((u & 0x80000000u) ? (u & 0x7FFFFFFFu) : ~u);
}

// ---------------- pass A: per-pixel stats + level-0 histogram ----------------
__global__ __launch_bounds__(256) void kA(const float* __restrict__ out_,
                                          const int* __restrict__ lab_,
                                          const float* __restrict__ tm_,
                                          unsigned* __restrict__ ws) {
  const int b = blockIdx.y;
  unsigned* wsb = ws + (size_t)b * PER_BATCH;
  float* wsbf = (float*)wsb;
  __shared__ unsigned sh_h[2048];
  __shared__ unsigned sh_kc[8], sh_tc[8];
  __shared__ float sh_ks[32];
  __shared__ unsigned sh_c[3];
  for (int i = threadIdx.x; i < 2048; i += 256) sh_h[i] = 0u;
  if (threadIdx.x < 8) { sh_kc[threadIdx.x] = 0u; sh_tc[threadIdx.x] = 0u; }
  if (threadIdx.x < 32) sh_ks[threadIdx.x] = 0.f;
  if (threadIdx.x < 3) sh_c[threadIdx.x] = 0u;
  __syncthreads();

  const float4* tx = (const float4*)(out_ + (size_t)b * 6 * NPIX);
  const float4* s0 = (const float4*)(out_ + (size_t)b * 6 * NPIX + 2 * (size_t)NPIX);
  const float4* s1 = (const float4*)(out_ + (size_t)b * 6 * NPIX + 3 * (size_t)NPIX);
  const float4* s2 = (const float4*)(out_ + (size_t)b * 6 * NPIX + 4 * (size_t)NPIX);
  const float4* s3 = (const float4*)(out_ + (size_t)b * 6 * NPIX + 5 * (size_t)NPIX);
  const int4* gt = (const int4*)(lab_ + (size_t)b * 2 * NPIX);
  const int4* gk = (const int4*)(lab_ + (size_t)b * 2 * NPIX + NPIX);
  const float4* tmv = (const float4*)(tm_ + (size_t)b * NPIX);

  unsigned cpos = 0, cposm = 0, cneg = 0;
  const int nv = NPIX / 4;
  for (int i = blockIdx.x * blockDim.x + threadIdx.x; i < nv; i += gridDim.x * blockDim.x) {
    float4 t4 = tx[i]; int4 g4 = gt[i]; int4 k4 = gk[i]; float4 m4 = tmv[i];
    float4 a0 = s0[i], a1 = s1[i], a2 = s2[i], a3 = s3[i];
#pragma unroll
    for (int j = 0; j < 4; ++j) {
      float tv = ((const float*)&t4)[j];
      int gtv = ((const int*)&g4)[j];
      int gkv = ((const int*)&k4)[j];
      float mv = ((const float*)&m4)[j];
      if (gtv > 0) {
        ++cpos;
        if (mv <= 0.5f) ++cposm;
        atomicAdd(&sh_tc[gtv & 7], 1u);
      } else {
        ++cneg;
        unsigned key = mapf(tv);
        atomicAdd(&sh_h[key >> 21], 1u);
      }
      if (gkv > 0) {
        int kk = gkv & 7;
        atomicAdd(&sh_kc[kk], 1u);
        atomicAdd(&sh_ks[kk * 4 + 0], ((const float*)&a0)[j]);
        atomicAdd(&sh_ks[kk * 4 + 1], ((const float*)&a1)[j]);
        atomicAdd(&sh_ks[kk * 4 + 2], ((const float*)&a2)[j]);
        atomicAdd(&sh_ks[kk * 4 + 3], ((const float*)&a3)[j]);
      }
    }
  }
  atomicAdd(&sh_c[0], cpos); atomicAdd(&sh_c[1], cposm); atomicAdd(&sh_c[2], cneg);
  __syncthreads();
  for (int i = threadIdx.x; i < 2048; i += 256) {
    unsigned v = sh_h[i]; if (v) atomicAdd(&wsb[OFF_H0 + i], v);
  }
  if (threadIdx.x < 8) {
    if (sh_kc[threadIdx.x]) atomicAdd(&wsb[OFF_KC + threadIdx.x], sh_kc[threadIdx.x]);
    if (sh_tc[threadIdx.x]) atomicAdd(&wsb[OFF_TC + threadIdx.x], sh_tc[threadIdx.x]);
  }
  if (threadIdx.x < 32) {
    float v = sh_ks[threadIdx.x];
    if (v != 0.f) atomicAdd(&wsbf[OFF_KS + threadIdx.x], v);
  }
  if (threadIdx.x == 0) {
    atomicAdd(&wsb[OFF_CPOS], sh_c[0]);
    atomicAdd(&wsb[OFF_CPOSM], sh_c[1]);
    atomicAdd(&wsb[OFF_CNEG], sh_c[2]);
  }
}

// ------- pass B: scalars, centroids, loss_dis, scan level-0 histogram -------
__global__ void kB(unsigned* __restrict__ ws) {
  const int b = blockIdx.x;
  unsigned* wsb = ws + (size_t)b * PER_BATCH;
  float* wsbf = (float*)wsb;
  __shared__ unsigned S[256];
  __shared__ unsigned sh_k;
  __shared__ int sh_fall;
  const int tid = threadIdx.x;
  if (tid == 0) {
    long cpos = (long)wsb[OFF_CPOS], cposm = (long)wsb[OFF_CPOSM], cneg = (long)wsb[OFF_CNEG];
    long posnum = cpos - cposm;
    long negnum = posnum * 3; if (negnum > cneg) negnum = cneg;
    int fall = (posnum == 0) || (negnum == 0);
    wsb[OFF_NEGNUM] = (unsigned)negnum;
    wsb[OFF_FALL] = (unsigned)fall;
    sh_k = (unsigned)negnum; sh_fall = fall;
    // centroids, valid set
    unsigned nvv = 0, vmask = 0;
    for (int k = 1; k < 8; ++k) {
      unsigned kc = wsb[OFF_KC + k], tc = wsb[OFF_TC + k];
      float inv = 1.f / fmaxf((float)kc, 1.f);
      for (int c = 0; c < 4; ++c) wsbf[OFF_G + k * 4 + c] = wsbf[OFF_KS + k * 4 + c] * inv;
      if (kc > 0 && tc > 0) { vmask |= (1u << k); ++nvv; }
    }
    wsb[OFF_NV] = nvv; wsb[OFF_VM] = vmask;
    // loss_dis over valid pairs
    float s = 0.f;
    for (int i = 1; i < 8; ++i) {
      if (!((vmask >> i) & 1)) continue;
      for (int j = i + 1; j < 8; ++j) {
        if (!((vmask >> j) & 1)) continue;
        float sq = 0.f;
        for (int c = 0; c < 4; ++c) {
          float d = wsbf[OFF_G + i * 4 + c] - wsbf[OFF_G + j * 4 + c];
          sq += d * d;
        }
        float gn = (sq > 0.f) ? sqrtf(sq) : 0.f;
        float dd = fmaxf(3.0f - gn, 0.f);
        s += log1pf(dd * dd);
      }
    }
    float denom = (float)(nvv * (nvv > 0 ? nvv - 1u : 0u));
    wsbf[OFF_LDIS] = (nvv > 1) ? (s / fmaxf(denom, 1.f)) : 0.f;
    if (fall) wsb[OFF_PFX0] = 0xFFFFFFFFu;
  }
  __syncthreads();
  if (sh_fall) return;
  unsigned p = 0;
#pragma unroll
  for (int j = 0; j < 8; ++j) p += wsb[OFF_H0 + tid * 8 + j];
  S[tid] = p;
  __syncthreads();
  if (tid == 0) {
    unsigned k = sh_k, cum = 0; int seg = 0;
    for (int t = 255; t >= 0; --t) { cum += S[t]; if (cum >= k) { seg = t; k -= (cum - S[t]); break; } }
    unsigned cum2 = 0; int bin = seg * 8;
    for (int j = 7; j >= 0; --j) {
      unsigned h = wsb[OFF_H0 + seg * 8 + j]; cum2 += h;
      if (cum2 >= k) { bin = seg * 8 + j; k -= (cum2 - h); break; }
    }
    wsb[OFF_PFX0] = (unsigned)bin;
    wsb[OFF_K1] = k;
  }
}

// ---------------- pass C: level-1 histogram (bits 20..10) ----------------
__global__ __launch_bounds__(256) void kC(const float* __restrict__ out_,
                                          const int* __restrict__ lab_,
                                          unsigned* __restrict__ ws) {
  const int b = blockIdx.y;
  unsigned* wsb = ws + (size_t)b * PER_BATCH;
  const unsigned pfx = wsb[OFF_PFX0];
  if (pfx == 0xFFFFFFFFu) return;
  __shared__ unsigned sh_h[2048];
  for (int i = threadIdx.x; i < 2048; i += 256) sh_h[i] = 0u;
  __syncthreads();
  const float4* tx = (const float4*)(out_ + (size_t)b * 6 * NPIX);
  const int4* gt = (const int4*)(lab_ + (size_t)b * 2 * NPIX);
  const int nv = NPIX / 4;
  for (int i = blockIdx.x * blockDim.x + threadIdx.x; i < nv; i += gridDim.x * blockDim.x) {
    float4 t4 = tx[i]; int4 g4 = gt[i];
#pragma unroll
    for (int j = 0; j < 4; ++j) {
      float tv = ((const float*)&t4)[j];
      int gtv = ((const int*)&g4)[j];
      if (gtv <= 0) {
        unsigned key = mapf(tv);
        if ((key >> 21) == pfx) atomicAdd(&sh_h[(key >> 10) & 0x7FFu], 1u);
      }
    }
  }
  __syncthreads();
  for (int i = threadIdx.x; i < 2048; i += 256) {
    unsigned v = sh_h[i]; if (v) atomicAdd(&wsb[OFF_H1 + i], v);
  }
}

// ---------------- pass D: scan level-1 ----------------
__global__ void kD(unsigned* __restrict__ ws) {
  const int b = blockIdx.x;
  unsigned* wsb = ws + (size_t)b * PER_BATCH;
  if (wsb[OFF_FALL]) return;
  __shared__ unsigned S[256];
  const int tid = threadIdx.x;
  unsigned p = 0;
#pragma unroll
  for (int j = 0; j < 8; ++j) p += wsb[OFF_H1 + tid * 8 + j];
  S[tid] = p;
  __syncthreads();
  if (tid == 0) {
    unsigned k = wsb[OFF_K1], cum = 0; int seg = 0;
    for (int t = 255; t >= 0; --t) { cum += S[t]; if (cum >= k) { seg = t; k -= (cum - S[t]); break; } }
    unsigned cum2 = 0; int bin = seg * 8;
    for (int j = 7; j >= 0; --j) {
      unsigned h = wsb[OFF_H1 + seg * 8 + j]; cum2 += h;
      if (cum2 >= k) { bin = seg * 8 + j; k -= (cum2 - h); break; }
    }
    wsb[OFF_PFX1] = (unsigned)bin;
    wsb[OFF_K2] = k;
  }
}

// ---------------- pass E: level-2 histogram (bits 9..0) ----------------
__global__ __launch_bounds__(256) void kE(const float* __restrict__ out_,
                                          const int* __restrict__ lab_,
                                          unsigned* __restrict__ ws) {
  const int b = blockIdx.y;
  unsigned* wsb = ws + (size_t)b * PER_BATCH;
  if (wsb[OFF_FALL]) return;
  const unsigned pfx22 = (wsb[OFF_PFX0] << 11) | wsb[OFF_PFX1];
  __shared__ unsigned sh_h[1024];
  for (int i = threadIdx.x; i < 1024; i += 256) sh_h[i] = 0u;
  __syncthreads();
  const float4* tx = (const float4*)(out_ + (size_t)b * 6 * NPIX);
  const int4* gt = (const int4*)(lab_ + (size_t)b * 2 * NPIX);
  const int nv = NPIX / 4;
  for (int i = blockIdx.x * blockDim.x + threadIdx.x; i < nv; i += gridDim.x * blockDim.x) {
    float4 t4 = tx[i]; int4 g4 = gt[i];
#pragma unroll
    for (int j = 0; j < 4; ++j) {
      float tv = ((const float*)&t4)[j];
      int gtv = ((const int*)&g4)[j];
      if (gtv <= 0) {
        unsigned key = mapf(tv);
        if ((key >> 10) == pfx22) atomicAdd(&sh_h[key & 0x3FFu], 1u);
      }
    }
  }
  __syncthreads();
  for (int i = threadIdx.x; i < 1024; i += 256) {
    unsigned v = sh_h[i]; if (v) atomicAdd(&wsb[OFF_H2 + i], v);
  }
}

// ---------------- pass F: scan level-2 -> threshold ----------------
__global__ void kF(unsigned* __restrict__ ws) {
  const int b = blockIdx.x;
  unsigned* wsb = ws + (size_t)b * PER_BATCH;
  float* wsbf = (float*)wsb;
  const int tid = threadIdx.x;
  if (wsb[OFF_FALL]) { if (tid == 0) wsbf[OFF_TH] = 0.f; return; }
  __shared__ unsigned S[256];
  unsigned p = 0;
#pragma unroll
  for (int j = 0; j < 4; ++j) p += wsb[OFF_H2 + tid * 4 + j];
  S[tid] = p;
  __syncthreads();
  if (tid == 0) {
    unsigned k = wsb[OFF_K2], cum = 0; int seg = 0;
    for (int t = 255; t >= 0; --t) { cum += S[t]; if (cum >= k) { seg = t; k -= (cum - S[t]); break; } }
    unsigned cum2 = 0; int bin = seg * 4;
    for (int j = 3; j >= 0; --j) {
      unsigned h = wsb[OFF_H2 + seg * 4 + j]; cum2 += h;
      if (cum2 >= k) { bin = seg * 4 + j; break; }
    }
    unsigned key = (wsb[OFF_PFX0] << 21) | (wsb[OFF_PFX1] << 10) | (unsigned)bin;
    wsbf[OFF_TH] = unmapf(key);
  }
}

// ---------------- pass G: agg loss + both dice sums ----------------
__global__ __launch_bounds__(256) void kG(const float* __restrict__ out_,
                                          const int* __restrict__ lab_,
                                          const float* __restrict__ tm_,
                                          unsigned* __restrict__ ws) {
  const int b = blockIdx.y;
  unsigned* wsb = ws + (size_t)b * PER_BATCH;
  float* wsbf = (float*)wsb;
  __shared__ float sG[32];
  __shared__ float sAgg[8];
  __shared__ float sD[6];
  __shared__ float sTh;
  __shared__ int sFall;
  if (threadIdx.x < 32) sG[threadIdx.x] = wsbf[OFF_G + threadIdx.x];
  if (threadIdx.x < 8) sAgg[threadIdx.x] = 0.f;
  if (threadIdx.x < 6) sD[threadIdx.x] = 0.f;
  if (threadIdx.x == 0) { sTh = wsbf[OFF_TH]; sFall = (int)wsb[OFF_FALL]; }
  __syncthreads();
  const float th = sTh;
  const int fall = sFall;

  const float4* tx = (const float4*)(out_ + (size_t)b * 6 * NPIX);
  const float4* kr = (const float4*)(out_ + (size_t)b * 6 * NPIX + (size_t)NPIX);
  const float4* s0 = (const float4*)(out_ + (size_t)b * 6 * NPIX + 2 * (size_t)NPIX);
  const float4* s1 = (const float4*)(out_ + (size_t)b * 6 * NPIX + 3 * (size_t)NPIX);
  const float4* s2 = (const float4*)(out_ + (size_t)b * 6 * NPIX + 4 * (size_t)NPIX);
  const float4* s3 = (const float4*)(out_ + (size_t)b * 6 * NPIX + 5 * (size_t)NPIX);
  const int4* gt = (const int4*)(lab_ + (size_t)b * 2 * NPIX);
  const int4* gk = (const int4*)(lab_ + (size_t)b * 2 * NPIX + NPIX);
  const float4* tmv = (const float4*)(tm_ + (size_t)b * NPIX);

  float at = 0.f, bt = 0.f, ct = 0.f, ak = 0.f, bk = 0.f, ck = 0.f;
  const int nv = NPIX / 4;
  for (int i = blockIdx.x * blockDim.x + threadIdx.x; i < nv; i += gridDim.x * blockDim.x) {
    float4 t4 = tx[i], q4 = kr[i], m4 = tmv[i];
    int4 g4 = gt[i], k4 = gk[i];
    float4 a0 = s0[i], a1 = s1[i], a2 = s2[i], a3 = s3[i];
#pragma unroll
    for (int j = 0; j < 4; ++j) {
      float tv = ((const float*)&t4)[j];
      float kv = ((const float*)&q4)[j];
      float mv = ((const float*)&m4)[j];
      int gtv = ((const int*)&g4)[j];
      int gkv = ((const int*)&k4)[j];
      float st = 1.f / (1.f + expf(-tv));
      float sel = fall ? mv : ((((tv >= th) || (gtv > 0)) && (mv > 0.5f)) ? 1.f : 0.f);
      float p = st * sel;
      float tt = (gtv > 0) ? sel : 0.f;
      at += p * tt; bt += p * p; ct += tt * tt;
      float sk2 = 1.f / (1.f + expf(-kv));
      float selk = ((st > 0.5f) && (mv > 0.5f)) ? 1.f : 0.f;
      float pk = sk2 * selk;
      float tk = (gkv > 0) ? selk : 0.f;
      ak += pk * tk; bk += pk * pk; ck += tk * tk;
      if (gtv > 0) {
        int kk = gtv & 7;
        float d0 = ((const float*)&a0)[j] - sG[kk * 4 + 0];
        float d1 = ((const float*)&a1)[j] - sG[kk * 4 + 1];
        float d2 = ((const float*)&a2)[j] - sG[kk * 4 + 2];
        float d3 = ((const float*)&a3)[j] - sG[kk * 4 + 3];
        float sq = d0 * d0 + d1 * d1 + d2 * d2 + d3 * d3;
        float d = (sq > 0.f) ? sqrtf(sq) : 0.f;
        float dd = fmaxf(d - 0.5f, 0.f);
        atomicAdd(&sAgg[kk], log1pf(dd * dd));
      }
    }
  }
  atomicAdd(&sD[0], at); atomicAdd(&sD[1], bt); atomicAdd(&sD[2], ct);
  atomicAdd(&sD[3], ak); atomicAdd(&sD[4], bk); atomicAdd(&sD[5], ck);
  __syncthreads();
  if (threadIdx.x < 8) {
    float v = sAgg[threadIdx.x];
    if (v != 0.f) atomicAdd(&wsbf[OFF_AGG + threadIdx.x], v);
  }
  if (threadIdx.x < 6) atomicAdd(&wsbf[OFF_DICE + threadIdx.x], sD[threadIdx.x]);
}

// ---------------- pass H: finalize 5 scalars ----------------
__global__ void kH(const unsigned* __restrict__ ws, float* __restrict__ out) {
  __shared__ float sv[4][8];
  const int b = threadIdx.x;
  if (b < 8) {
    const unsigned* wsb = ws + (size_t)b * PER_BATCH;
    const float* wsbf = (const float*)wsb;
    float at = wsbf[OFF_DICE + 0], bt = wsbf[OFF_DICE + 1] + 1e-3f, ct = wsbf[OFF_DICE + 2] + 1e-3f;
    float lt = 1.f - 2.f * at / (bt + ct);
    float ak = wsbf[OFF_DICE + 3], bk = wsbf[OFF_DICE + 4] + 1e-3f, ck = wsbf[OFF_DICE + 5] + 1e-3f;
    float lk = 1.f - 2.f * ak / (bk + ck);
    unsigned vm = wsb[OFF_VM], nvv = wsb[OFF_NV];
    float s = 0.f;
    for (int k = 1; k < 8; ++k)
      if ((vm >> k) & 1) s += wsbf[OFF_AGG + k] / fmaxf((float)wsb[OFF_TC + k], 1.f);
    float la = s / fmaxf((float)nvv, 1.f);
    float ld = wsbf[OFF_LDIS];
    sv[0][b] = lt; sv[1][b] = lk; sv[2][b] = la; sv[3][b] = ld;
  }
  __syncthreads();
  if (threadIdx.x == 0) {
    float mt = 0.f, mk = 0.f, ma = 0.f, md = 0.f;
    for (int i = 0; i < 8; ++i) { mt += sv[0][i]; mk += sv[1][i]; ma += sv[2][i]; md += sv[3][i]; }
    mt *= 0.125f; mk *= 0.125f; ma *= 0.125f; md *= 0.125f;
    out[0] = mt + 0.5f * mk + 0.25f * (ma + md);
    out[1] = mt;
    out[2] = mk;
    out[3] = ma;
    out[4] = md;
  }
}

extern "C" void kernel_launch(void* const* d_in, const int* in_sizes, int n_in,
                              void* d_out, int out_size, void* d_ws, size_t ws_size,
                              hipStream_t stream) {
  const float* outputs = (const float*)d_in[0];
  const int* labels = (const int*)d_in[1];
  const float* tm = (const float*)d_in[2];
  unsigned* ws = (unsigned*)d_ws;
  float* out = (float*)d_out;

  hipMemsetAsync(d_ws, 0, (size_t)NB * PER_BATCH * sizeof(unsigned), stream);

  dim3 blk(256);
  dim3 gridP(100, NB);  // 100*256 threads/batch, each does exactly 4 float4 iters
  kA<<<gridP, blk, 0, stream>>>(outputs, labels, tm, ws);
  kB<<<NB, 256, 0, stream>>>(ws);
  kC<<<gridP, blk, 0, stream>>>(outputs, labels, ws);
  kD<<<NB, 256, 0, stream>>>(ws);
  kE<<<gridP, blk, 0, stream>>>(outputs, labels, ws);
  kF<<<NB, 256, 0, stream>>>(ws);
  kG<<<gridP, blk, 0, stream>>>(outputs, labels, tm, ws);
  kH<<<1, 64, 0, stream>>>(ws, out);
}

// Round 2
// 111.426 us; speedup vs baseline: 1.8695x; 1.8695x over previous
//
#include <hip/hip_runtime.h>

#define NPIX 409600   // 640*640
#define NB 8          // batch

// ---------------- workspace layout (4-byte words, per batch) ----------------
constexpr int OFF_H0    = 0;     // 2048 u32  level-0 histogram (key bits 31..21)
constexpr int OFF_H1    = 2048;  // 2048 u32  level-1 histogram (key bits 20..10)
constexpr int OFF_H2    = 4096;  // 1024 u32  level-2 histogram (key bits 9..0)
constexpr int OFF_KC    = 5120;  // 8 u32     kernel-mask counts per instance
constexpr int OFF_TC    = 5128;  // 8 u32     text-mask counts per instance
constexpr int OFF_KS    = 5136;  // 32 f32    kernel-mask sim sums (inst*4+c)
constexpr int OFF_AGG   = 5168;  // 8 f32     per-instance sum log1p(D)
constexpr int OFF_CPOS  = 5176;  // u32
constexpr int OFF_CPOSM = 5177;  // u32  pos & tm<=0.5
constexpr int OFF_CNEG  = 5178;  // u32
constexpr int OFF_NEGNUM= 5179;  // u32
constexpr int OFF_PFX0  = 5180;  // u32  (0xFFFFFFFF = fallback sentinel)
constexpr int OFF_K1    = 5181;  // u32
constexpr int OFF_PFX1  = 5182;  // u32
constexpr int OFF_K2    = 5183;  // u32
constexpr int OFF_TH    = 5184;  // f32  OHEM threshold
constexpr int OFF_FALL  = 5185;  // u32  fallback flag
constexpr int OFF_G     = 5186;  // 32 f32 centroids
constexpr int OFF_NV    = 5218;  // u32 n_valid
constexpr int OFF_VM    = 5219;  // u32 valid bitmask
constexpr int OFF_LDIS  = 5220;  // f32
constexpr int OFF_DICE  = 5221;  // 6 f32: at,bt,ct,ak,bk,ck
constexpr int PER_BATCH = 5376;  // padded

// map float -> uint monotone ascending (larger float -> larger key)
__device__ __forceinline__ unsigned mapf(float s) {
  unsigned b = __float_as_uint(s);
  return (b & 0x80000000u) ? ~b : (b | 0x80000000u);
}
__device__ __forceinline__ float unmapf(unsigned u) {
  return __uint_as_float((u & 0x80000000u) ? (u & 0x7FFFFFFFu) : ~u);
}

__device__ __forceinline__ float wredf(float v) {
#pragma unroll
  for (int m = 32; m >= 1; m >>= 1) v += __shfl_xor(v, m, 64);
  return v;
}
__device__ __forceinline__ unsigned wredu(unsigned v) {
#pragma unroll
  for (int m = 32; m >= 1; m >>= 1) v += (unsigned)__shfl_xor((int)v, m, 64);
  return v;
}

// ---------------- pass A: per-pixel stats + level-0 histogram ----------------
// Per-thread register accumulation (7-way unrolled compare-select) instead of
// per-pixel LDS atomics: instance ids collide ~9 lanes/address -> ~45
// serialized LDS ops/pixel was the R0 bottleneck (100us @ 6.6% HBM).
__global__ __launch_bounds__(256, 4) void kA(const float* __restrict__ out_,
                                             const int* __restrict__ lab_,
                                             const float* __restrict__ tm_,
                                             unsigned* __restrict__ ws) {
  const int b = blockIdx.y;
  unsigned* wsb = ws + (size_t)b * PER_BATCH;
  float* wsbf = (float*)wsb;
  __shared__ unsigned sh_h[2048];
  __shared__ unsigned sh_kc[7], sh_tc[7];
  __shared__ float sh_ks[28];
  __shared__ unsigned sh_c[3];
  for (int i = threadIdx.x; i < 2048; i += 256) sh_h[i] = 0u;
  if (threadIdx.x < 7) { sh_kc[threadIdx.x] = 0u; sh_tc[threadIdx.x] = 0u; }
  if (threadIdx.x < 28) sh_ks[threadIdx.x] = 0.f;
  if (threadIdx.x < 3) sh_c[threadIdx.x] = 0u;
  __syncthreads();

  const float4* tx = (const float4*)(out_ + (size_t)b * 6 * NPIX);
  const float4* s0 = (const float4*)(out_ + (size_t)b * 6 * NPIX + 2 * (size_t)NPIX);
  const float4* s1 = (const float4*)(out_ + (size_t)b * 6 * NPIX + 3 * (size_t)NPIX);
  const float4* s2 = (const float4*)(out_ + (size_t)b * 6 * NPIX + 4 * (size_t)NPIX);
  const float4* s3 = (const float4*)(out_ + (size_t)b * 6 * NPIX + 5 * (size_t)NPIX);
  const int4* gt = (const int4*)(lab_ + (size_t)b * 2 * NPIX);
  const int4* gk = (const int4*)(lab_ + (size_t)b * 2 * NPIX + NPIX);
  const float4* tmv = (const float4*)(tm_ + (size_t)b * NPIX);

  unsigned cpos = 0, cposm = 0, cneg = 0;
  unsigned kcnt[7], tcnt[7];
  float ks0[7], ks1[7], ks2[7], ks3[7];
#pragma unroll
  for (int k = 0; k < 7; ++k) {
    kcnt[k] = 0u; tcnt[k] = 0u;
    ks0[k] = 0.f; ks1[k] = 0.f; ks2[k] = 0.f; ks3[k] = 0.f;
  }

  const int nv = NPIX / 4;
  for (int i = blockIdx.x * blockDim.x + threadIdx.x; i < nv; i += gridDim.x * blockDim.x) {
    float4 t4 = tx[i]; int4 g4 = gt[i]; int4 k4 = gk[i]; float4 m4 = tmv[i];
    float4 a0 = s0[i], a1 = s1[i], a2 = s2[i], a3 = s3[i];
#pragma unroll
    for (int j = 0; j < 4; ++j) {
      float tv = ((const float*)&t4)[j];
      int gtv = ((const int*)&g4)[j];
      int gkv = ((const int*)&k4)[j];
      float mv = ((const float*)&m4)[j];
      float v0 = ((const float*)&a0)[j], v1 = ((const float*)&a1)[j];
      float v2 = ((const float*)&a2)[j], v3 = ((const float*)&a3)[j];
      bool pos = gtv > 0;
      cpos += pos;
      cposm += (pos && (mv <= 0.5f));
      cneg += !pos;
      if (!pos) {
        unsigned key = mapf(tv);
        atomicAdd(&sh_h[key >> 21], 1u);  // 1/8 of pixels, spread bins: cheap
      }
#pragma unroll
      for (int k = 0; k < 7; ++k) {
        tcnt[k] += (gtv == k + 1);
        bool mk = (gkv == k + 1);
        kcnt[k] += mk;
        float sel = mk ? 1.f : 0.f;
        ks0[k] += sel * v0; ks1[k] += sel * v1; ks2[k] += sel * v2; ks3[k] += sel * v3;
      }
    }
  }

  // wave reduce -> per-wave LDS atomic -> per-block global atomic
  const int lane = threadIdx.x & 63;
  unsigned r;
  r = wredu(cpos);  if (lane == 0) atomicAdd(&sh_c[0], r);
  r = wredu(cposm); if (lane == 0) atomicAdd(&sh_c[1], r);
  r = wredu(cneg);  if (lane == 0) atomicAdd(&sh_c[2], r);
#pragma unroll
  for (int k = 0; k < 7; ++k) {
    r = wredu(kcnt[k]); if (lane == 0) atomicAdd(&sh_kc[k], r);
    r = wredu(tcnt[k]); if (lane == 0) atomicAdd(&sh_tc[k], r);
    float f;
    f = wredf(ks0[k]); if (lane == 0) atomicAdd(&sh_ks[k * 4 + 0], f);
    f = wredf(ks1[k]); if (lane == 0) atomicAdd(&sh_ks[k * 4 + 1], f);
    f = wredf(ks2[k]); if (lane == 0) atomicAdd(&sh_ks[k * 4 + 2], f);
    f = wredf(ks3[k]); if (lane == 0) atomicAdd(&sh_ks[k * 4 + 3], f);
  }
  __syncthreads();
  for (int i = threadIdx.x; i < 2048; i += 256) {
    unsigned v = sh_h[i]; if (v) atomicAdd(&wsb[OFF_H0 + i], v);
  }
  if (threadIdx.x < 7) {
    if (sh_kc[threadIdx.x]) atomicAdd(&wsb[OFF_KC + 1 + threadIdx.x], sh_kc[threadIdx.x]);
    if (sh_tc[threadIdx.x]) atomicAdd(&wsb[OFF_TC + 1 + threadIdx.x], sh_tc[threadIdx.x]);
  }
  if (threadIdx.x < 28) {
    float v = sh_ks[threadIdx.x];
    if (v != 0.f) atomicAdd(&wsbf[OFF_KS + 4 + threadIdx.x], v);
  }
  if (threadIdx.x == 0) {
    atomicAdd(&wsb[OFF_CPOS], sh_c[0]);
    atomicAdd(&wsb[OFF_CPOSM], sh_c[1]);
    atomicAdd(&wsb[OFF_CNEG], sh_c[2]);
  }
}

// ------- pass B: scalars, centroids, loss_dis, parallel scan level-0 -------
__global__ void kB(unsigned* __restrict__ ws) {
  const int b = blockIdx.x;
  unsigned* wsb = ws + (size_t)b * PER_BATCH;
  float* wsbf = (float*)wsb;
  __shared__ unsigned S[256];
  __shared__ unsigned sh_k;
  __shared__ int sh_fall;
  const int tid = threadIdx.x;
  if (tid == 0) {
    long cpos = (long)wsb[OFF_CPOS], cposm = (long)wsb[OFF_CPOSM], cneg = (long)wsb[OFF_CNEG];
    long posnum = cpos - cposm;
    long negnum = posnum * 3; if (negnum > cneg) negnum = cneg;
    int fall = (posnum == 0) || (negnum == 0);
    wsb[OFF_NEGNUM] = (unsigned)negnum;
    wsb[OFF_FALL] = (unsigned)fall;
    sh_k = (unsigned)negnum; sh_fall = fall;
    unsigned nvv = 0, vmask = 0;
    for (int k = 1; k < 8; ++k) {
      unsigned kc = wsb[OFF_KC + k], tc = wsb[OFF_TC + k];
      float inv = 1.f / fmaxf((float)kc, 1.f);
      for (int c = 0; c < 4; ++c) wsbf[OFF_G + k * 4 + c] = wsbf[OFF_KS + k * 4 + c] * inv;
      if (kc > 0 && tc > 0) { vmask |= (1u << k); ++nvv; }
    }
    wsb[OFF_NV] = nvv; wsb[OFF_VM] = vmask;
    float s = 0.f;
    for (int i = 1; i < 8; ++i) {
      if (!((vmask >> i) & 1)) continue;
      for (int j = i + 1; j < 8; ++j) {
        if (!((vmask >> j) & 1)) continue;
        float sq = 0.f;
        for (int c = 0; c < 4; ++c) {
          float d = wsbf[OFF_G + i * 4 + c] - wsbf[OFF_G + j * 4 + c];
          sq += d * d;
        }
        float gn = (sq > 0.f) ? sqrtf(sq) : 0.f;
        float dd = fmaxf(3.0f - gn, 0.f);
        s += log1pf(dd * dd);
      }
    }
    float denom = (float)(nvv * (nvv > 0 ? nvv - 1u : 0u));
    wsbf[OFF_LDIS] = (nvv > 1) ? (s / fmaxf(denom, 1.f)) : 0.f;
    if (fall) wsb[OFF_PFX0] = 0xFFFFFFFFu;
  }
  __syncthreads();
  if (sh_fall) return;
  unsigned p = 0;
#pragma unroll
  for (int j = 0; j < 8; ++j) p += wsb[OFF_H0 + tid * 8 + j];
  S[tid] = p;
  __syncthreads();
  // inclusive suffix scan (Hillis-Steele)
#pragma unroll
  for (int off = 1; off < 256; off <<= 1) {
    unsigned v = (tid + off < 256) ? S[tid + off] : 0u;
    __syncthreads();
    S[tid] += v;
    __syncthreads();
  }
  unsigned k = sh_k;
  unsigned suf = S[tid];
  unsigned sufn = suf - p;  // suffix sum strictly above this segment
  if (suf >= k && sufn < k) {
    unsigned kk = k - sufn;
    unsigned cum2 = 0; int bin = tid * 8;
    for (int j = 7; j >= 0; --j) {
      unsigned h = wsb[OFF_H0 + tid * 8 + j]; cum2 += h;
      if (cum2 >= kk) { bin = tid * 8 + j; kk -= (cum2 - h); break; }
    }
    wsb[OFF_PFX0] = (unsigned)bin;
    wsb[OFF_K1] = kk;
  }
}

// ---------------- pass C: level-1 histogram (bits 20..10) ----------------
__global__ __launch_bounds__(256) void kC(const float* __restrict__ out_,
                                          const int* __restrict__ lab_,
                                          unsigned* __restrict__ ws) {
  const int b = blockIdx.y;
  unsigned* wsb = ws + (size_t)b * PER_BATCH;
  const unsigned pfx = wsb[OFF_PFX0];
  if (pfx == 0xFFFFFFFFu) return;
  __shared__ unsigned sh_h[2048];
  for (int i = threadIdx.x; i < 2048; i += 256) sh_h[i] = 0u;
  __syncthreads();
  const float4* tx = (const float4*)(out_ + (size_t)b * 6 * NPIX);
  const int4* gt = (const int4*)(lab_ + (size_t)b * 2 * NPIX);
  const int nv = NPIX / 4;
  for (int i = blockIdx.x * blockDim.x + threadIdx.x; i < nv; i += gridDim.x * blockDim.x) {
    float4 t4 = tx[i]; int4 g4 = gt[i];
#pragma unroll
    for (int j = 0; j < 4; ++j) {
      float tv = ((const float*)&t4)[j];
      int gtv = ((const int*)&g4)[j];
      if (gtv <= 0) {
        unsigned key = mapf(tv);
        if ((key >> 21) == pfx) atomicAdd(&sh_h[(key >> 10) & 0x7FFu], 1u);
      }
    }
  }
  __syncthreads();
  for (int i = threadIdx.x; i < 2048; i += 256) {
    unsigned v = sh_h[i]; if (v) atomicAdd(&wsb[OFF_H1 + i], v);
  }
}

// ---------------- pass D: parallel scan level-1 ----------------
__global__ void kD(unsigned* __restrict__ ws) {
  const int b = blockIdx.x;
  unsigned* wsb = ws + (size_t)b * PER_BATCH;
  if (wsb[OFF_FALL]) return;
  __shared__ unsigned S[256];
  const int tid = threadIdx.x;
  unsigned p = 0;
#pragma unroll
  for (int j = 0; j < 8; ++j) p += wsb[OFF_H1 + tid * 8 + j];
  S[tid] = p;
  __syncthreads();
#pragma unroll
  for (int off = 1; off < 256; off <<= 1) {
    unsigned v = (tid + off < 256) ? S[tid + off] : 0u;
    __syncthreads();
    S[tid] += v;
    __syncthreads();
  }
  unsigned k = wsb[OFF_K1];
  unsigned suf = S[tid];
  unsigned sufn = suf - p;
  if (suf >= k && sufn < k) {
    unsigned kk = k - sufn;
    unsigned cum2 = 0; int bin = tid * 8;
    for (int j = 7; j >= 0; --j) {
      unsigned h = wsb[OFF_H1 + tid * 8 + j]; cum2 += h;
      if (cum2 >= kk) { bin = tid * 8 + j; kk -= (cum2 - h); break; }
    }
    wsb[OFF_PFX1] = (unsigned)bin;
    wsb[OFF_K2] = kk;
  }
}

// ---------------- pass E: level-2 histogram (bits 9..0) ----------------
__global__ __launch_bounds__(256) void kE(const float* __restrict__ out_,
                                          const int* __restrict__ lab_,
                                          unsigned* __restrict__ ws) {
  const int b = blockIdx.y;
  unsigned* wsb = ws + (size_t)b * PER_BATCH;
  if (wsb[OFF_FALL]) return;
  const unsigned pfx22 = (wsb[OFF_PFX0] << 11) | wsb[OFF_PFX1];
  __shared__ unsigned sh_h[1024];
  for (int i = threadIdx.x; i < 1024; i += 256) sh_h[i] = 0u;
  __syncthreads();
  const float4* tx = (const float4*)(out_ + (size_t)b * 6 * NPIX);
  const int4* gt = (const int4*)(lab_ + (size_t)b * 2 * NPIX);
  const int nv = NPIX / 4;
  for (int i = blockIdx.x * blockDim.x + threadIdx.x; i < nv; i += gridDim.x * blockDim.x) {
    float4 t4 = tx[i]; int4 g4 = gt[i];
#pragma unroll
    for (int j = 0; j < 4; ++j) {
      float tv = ((const float*)&t4)[j];
      int gtv = ((const int*)&g4)[j];
      if (gtv <= 0) {
        unsigned key = mapf(tv);
        if ((key >> 10) == pfx22) atomicAdd(&sh_h[key & 0x3FFu], 1u);
      }
    }
  }
  __syncthreads();
  for (int i = threadIdx.x; i < 1024; i += 256) {
    unsigned v = sh_h[i]; if (v) atomicAdd(&wsb[OFF_H2 + i], v);
  }
}

// ---------------- pass F: parallel scan level-2 -> threshold ----------------
__global__ void kF(unsigned* __restrict__ ws) {
  const int b = blockIdx.x;
  unsigned* wsb = ws + (size_t)b * PER_BATCH;
  float* wsbf = (float*)wsb;
  const int tid = threadIdx.x;
  if (wsb[OFF_FALL]) { if (tid == 0) wsbf[OFF_TH] = 0.f; return; }
  __shared__ unsigned S[256];
  unsigned p = 0;
#pragma unroll
  for (int j = 0; j < 4; ++j) p += wsb[OFF_H2 + tid * 4 + j];
  S[tid] = p;
  __syncthreads();
#pragma unroll
  for (int off = 1; off < 256; off <<= 1) {
    unsigned v = (tid + off < 256) ? S[tid + off] : 0u;
    __syncthreads();
    S[tid] += v;
    __syncthreads();
  }
  unsigned k = wsb[OFF_K2];
  unsigned suf = S[tid];
  unsigned sufn = suf - p;
  if (suf >= k && sufn < k) {
    unsigned kk = k - sufn;
    unsigned cum2 = 0; int bin = tid * 4;
    for (int j = 3; j >= 0; --j) {
      unsigned h = wsb[OFF_H2 + tid * 4 + j]; cum2 += h;
      if (cum2 >= kk) { bin = tid * 4 + j; break; }
    }
    unsigned key = (wsb[OFF_PFX0] << 21) | (wsb[OFF_PFX1] << 10) | (unsigned)bin;
    wsbf[OFF_TH] = unmapf(key);
  }
}

// ---------------- pass G: agg loss + both dice sums ----------------
__global__ __launch_bounds__(256, 4) void kG(const float* __restrict__ out_,
                                             const int* __restrict__ lab_,
                                             const float* __restrict__ tm_,
                                             unsigned* __restrict__ ws) {
  const int b = blockIdx.y;
  unsigned* wsb = ws + (size_t)b * PER_BATCH;
  float* wsbf = (float*)wsb;
  __shared__ float sG[32];
  __shared__ float sAgg[7];
  __shared__ float sD[6];
  __shared__ float sTh;
  __shared__ int sFall;
  if (threadIdx.x < 32) sG[threadIdx.x] = wsbf[OFF_G + threadIdx.x];
  if (threadIdx.x < 7) sAgg[threadIdx.x] = 0.f;
  if (threadIdx.x < 6) sD[threadIdx.x] = 0.f;
  if (threadIdx.x == 0) { sTh = wsbf[OFF_TH]; sFall = (int)wsb[OFF_FALL]; }
  __syncthreads();
  const float th = sTh;
  const int fall = sFall;

  const float4* tx = (const float4*)(out_ + (size_t)b * 6 * NPIX);
  const float4* kr = (const float4*)(out_ + (size_t)b * 6 * NPIX + (size_t)NPIX);
  const float4* s0 = (const float4*)(out_ + (size_t)b * 6 * NPIX + 2 * (size_t)NPIX);
  const float4* s1 = (const float4*)(out_ + (size_t)b * 6 * NPIX + 3 * (size_t)NPIX);
  const float4* s2 = (const float4*)(out_ + (size_t)b * 6 * NPIX + 4 * (size_t)NPIX);
  const float4* s3 = (const float4*)(out_ + (size_t)b * 6 * NPIX + 5 * (size_t)NPIX);
  const int4* gt = (const int4*)(lab_ + (size_t)b * 2 * NPIX);
  const int4* gk = (const int4*)(lab_ + (size_t)b * 2 * NPIX + NPIX);
  const float4* tmv = (const float4*)(tm_ + (size_t)b * NPIX);

  float at = 0.f, bt = 0.f, ct = 0.f, ak = 0.f, bk = 0.f, ck = 0.f;
  float agg[7];
#pragma unroll
  for (int k = 0; k < 7; ++k) agg[k] = 0.f;

  const int nv = NPIX / 4;
  for (int i = blockIdx.x * blockDim.x + threadIdx.x; i < nv; i += gridDim.x * blockDim.x) {
    float4 t4 = tx[i], q4 = kr[i], m4 = tmv[i];
    int4 g4 = gt[i], k4 = gk[i];
    float4 a0 = s0[i], a1 = s1[i], a2 = s2[i], a3 = s3[i];
#pragma unroll
    for (int j = 0; j < 4; ++j) {
      float tv = ((const float*)&t4)[j];
      float kv = ((const float*)&q4)[j];
      float mv = ((const float*)&m4)[j];
      int gtv = ((const int*)&g4)[j];
      int gkv = ((const int*)&k4)[j];
      bool pos = gtv > 0;
      float st = 1.f / (1.f + expf(-tv));
      float sel = fall ? mv : ((((tv >= th) || pos) && (mv > 0.5f)) ? 1.f : 0.f);
      float p = st * sel;
      float tt = pos ? sel : 0.f;
      at += p * tt; bt += p * p; ct += tt * tt;
      float sk2 = 1.f / (1.f + expf(-kv));
      float selk = ((st > 0.5f) && (mv > 0.5f)) ? 1.f : 0.f;
      float pk = sk2 * selk;
      float tk = (gkv > 0) ? selk : 0.f;
      ak += pk * tk; bk += pk * pk; ck += tk * tk;
      float lg = 0.f;
      if (pos) {
        int kk = gtv & 7;
        float d0 = ((const float*)&a0)[j] - sG[kk * 4 + 0];
        float d1 = ((const float*)&a1)[j] - sG[kk * 4 + 1];
        float d2 = ((const float*)&a2)[j] - sG[kk * 4 + 2];
        float d3 = ((const float*)&a3)[j] - sG[kk * 4 + 3];
        float sq = d0 * d0 + d1 * d1 + d2 * d2 + d3 * d3;
        float d = (sq > 0.f) ? sqrtf(sq) : 0.f;
        float dd = fmaxf(d - 0.5f, 0.f);
        lg = log1pf(dd * dd);
      }
#pragma unroll
      for (int k = 0; k < 7; ++k) agg[k] += (gtv == k + 1) ? lg : 0.f;
    }
  }

  const int lane = threadIdx.x & 63;
  float f;
  f = wredf(at); if (lane == 0) atomicAdd(&sD[0], f);
  f = wredf(bt); if (lane == 0) atomicAdd(&sD[1], f);
  f = wredf(ct); if (lane == 0) atomicAdd(&sD[2], f);
  f = wredf(ak); if (lane == 0) atomicAdd(&sD[3], f);
  f = wredf(bk); if (lane == 0) atomicAdd(&sD[4], f);
  f = wredf(ck); if (lane == 0) atomicAdd(&sD[5], f);
#pragma unroll
  for (int k = 0; k < 7; ++k) {
    f = wredf(agg[k]); if (lane == 0) atomicAdd(&sAgg[k], f);
  }
  __syncthreads();
  if (threadIdx.x < 7) {
    float v = sAgg[threadIdx.x];
    if (v != 0.f) atomicAdd(&wsbf[OFF_AGG + 1 + threadIdx.x], v);
  }
  if (threadIdx.x < 6) atomicAdd(&wsbf[OFF_DICE + threadIdx.x], sD[threadIdx.x]);
}

// ---------------- pass H: finalize 5 scalars ----------------
__global__ void kH(const unsigned* __restrict__ ws, float* __restrict__ out) {
  __shared__ float sv[4][8];
  const int b = threadIdx.x;
  if (b < 8) {
    const unsigned* wsb = ws + (size_t)b * PER_BATCH;
    const float* wsbf = (const float*)wsb;
    float at = wsbf[OFF_DICE + 0], bt = wsbf[OFF_DICE + 1] + 1e-3f, ct = wsbf[OFF_DICE + 2] + 1e-3f;
    float lt = 1.f - 2.f * at / (bt + ct);
    float ak = wsbf[OFF_DICE + 3], bk = wsbf[OFF_DICE + 4] + 1e-3f, ck = wsbf[OFF_DICE + 5] + 1e-3f;
    float lk = 1.f - 2.f * ak / (bk + ck);
    unsigned vm = wsb[OFF_VM], nvv = wsb[OFF_NV];
    float s = 0.f;
    for (int k = 1; k < 8; ++k)
      if ((vm >> k) & 1) s += wsbf[OFF_AGG + k] / fmaxf((float)wsb[OFF_TC + k], 1.f);
    float la = s / fmaxf((float)nvv, 1.f);
    float ld = wsbf[OFF_LDIS];
    sv[0][b] = lt; sv[1][b] = lk; sv[2][b] = la; sv[3][b] = ld;
  }
  __syncthreads();
  if (threadIdx.x == 0) {
    float mt = 0.f, mk = 0.f, ma = 0.f, md = 0.f;
    for (int i = 0; i < 8; ++i) { mt += sv[0][i]; mk += sv[1][i]; ma += sv[2][i]; md += sv[3][i]; }
    mt *= 0.125f; mk *= 0.125f; ma *= 0.125f; md *= 0.125f;
    out[0] = mt + 0.5f * mk + 0.25f * (ma + md);
    out[1] = mt;
    out[2] = mk;
    out[3] = ma;
    out[4] = md;
  }
}

extern "C" void kernel_launch(void* const* d_in, const int* in_sizes, int n_in,
                              void* d_out, int out_size, void* d_ws, size_t ws_size,
                              hipStream_t stream) {
  const float* outputs = (const float*)d_in[0];
  const int* labels = (const int*)d_in[1];
  const float* tm = (const float*)d_in[2];
  unsigned* ws = (unsigned*)d_ws;
  float* out = (float*)d_out;

  hipMemsetAsync(d_ws, 0, (size_t)NB * PER_BATCH * sizeof(unsigned), stream);

  dim3 blk(256);
  dim3 gridP(128, NB);  // 1024 blocks = 4/CU
  kA<<<gridP, blk, 0, stream>>>(outputs, labels, tm, ws);
  kB<<<NB, 256, 0, stream>>>(ws);
  kC<<<gridP, blk, 0, stream>>>(outputs, labels, ws);
  kD<<<NB, 256, 0, stream>>>(ws);
  kE<<<gridP, blk, 0, stream>>>(outputs, labels, ws);
  kF<<<NB, 256, 0, stream>>>(ws);
  kG<<<gridP, blk, 0, stream>>>(outputs, labels, tm, ws);
  kH<<<1, 64, 0, stream>>>(ws, out);
}